// Round 1
// baseline (569.785 us; speedup 1.0000x reference)
//
#include <hip/hip_runtime.h>

typedef __attribute__((ext_vector_type(8))) _Float16 f16x8;
typedef __attribute__((ext_vector_type(4))) _Float16 f16x4;
typedef __attribute__((ext_vector_type(4))) float f32x4;

#define N_B 64
#define T_F 300
#define TB 4
#define NT (T_F/TB)

// ws byte offsets
#define AY_OFF  0        // f16 [4][128][8]    y-GEMM A operand, K-chunked
#define WH_OFF  8192     // f16 [96][32]       folded mlp weight, rows (s-1)*3+c for s=1..5 (15 used)
#define OWC_OFF 14336    // f16 [6][12][96][8] folded out weight, chunked
#define BP_OFF  124928   // float[96]
#define OB_OFF  125312   // float[96]
#define W2_OFF  125696   // float[96][32][4]   diag weights W2[o][v][c] (c<3 used), = inv1*(W[o,0,c] + sum_{s>=2} W[o,s,c]*dv_s(v)^2)

__device__ __constant__ int EDGES[24][2] = {
  {1,2},{2,21},{3,21},{4,3},{5,21},{6,5},{7,6},{8,7},{9,21},{10,9},{11,10},{12,11},
  {13,1},{14,13},{15,14},{16,15},{17,1},{18,17},{19,18},{20,19},{22,23},{23,8},{24,25},{25,12}
};

// One setup kernel: block 0 does the 25-node BFS + Ay/W2; all blocks fold BN weights.
__global__ void setup_kernel(const float* __restrict__ mlp_w, const float* __restrict__ mlp_b,
    const float* __restrict__ g1, const float* __restrict__ be1,
    const float* __restrict__ mu1, const float* __restrict__ va1,
    const float* __restrict__ out_w, const float* __restrict__ out_b,
    const float* __restrict__ g2, const float* __restrict__ be2,
    const float* __restrict__ mu2, const float* __restrict__ va2,
    char* __restrict__ wsb) {
  _Float16* Ay  = (_Float16*)(wsb + AY_OFF);
  _Float16* Wh  = (_Float16*)(wsb + WH_OFF);
  _Float16* OWc = (_Float16*)(wsb + OWC_OFF);
  float* bp  = (float*)(wsb + BP_OFF);
  float* ob  = (float*)(wsb + OB_OFF);
  float* W2  = (float*)(wsb + W2_OFF);
  int tid = threadIdx.x;

  if (blockIdx.x == 0) {
    // A_large = J5 (x) B with B = A+I  =>  scale s reduces to 25-node graph:
    //   s=0: A_s = I;  s=1: M = J(x)B;  s>=2: M = J(x)(R_s\R_{s-1}) + I.
    __shared__ unsigned int Rk[6][25];
    __shared__ unsigned int Gs[6][25];
    __shared__ float dv[6][25];
    if (tid < 25) {
      unsigned int m = 1u << tid;
      for (int e = 0; e < 24; ++e) {
        int a = EDGES[e][0]-1, b = EDGES[e][1]-1;
        if (a == tid) m |= 1u<<b;
        if (b == tid) m |= 1u<<a;
      }
      Gs[1][tid] = m;   // B masks (incl. self)
      Rk[1][tid] = m;
    }
    __syncthreads();
    for (int k = 2; k <= 5; ++k) {
      if (tid < 25) {
        unsigned int p = Rk[k-1][tid], nm = p;
        for (int j = 0; j < 25; ++j) if ((p>>j)&1u) nm |= Gs[1][j];
        Rk[k][tid] = nm;
      }
      __syncthreads();
    }
    if (tid < 25) {
      for (int s = 1; s <= 5; ++s) {
        unsigned int g = (s==1) ? Gs[1][tid] : (Rk[s][tid] & ~Rk[s-1][tid]);
        if (s >= 2) Gs[s][tid] = g;
        int d = 5*__popc(g) + ((s>=2)?1:0);
        dv[s][tid] = (d>0) ? (float)(1.0/sqrt((double)d)) : 0.0f;
      }
    }
    __syncthreads();
    // Ay: [kc=0..3][row=0..127][j=0..7], row=(s-1)*25+v for s=1..5, i = kc*8+j
    for (int idx = tid; idx < 4096; idx += 256) {
      int kc = idx >> 10, row = (idx>>3)&127, j = idx&7;
      int i = kc*8 + j;
      float val = 0.f;
      if (row < 125 && i < 25) {
        int s = 1 + row/25, v = row - (s-1)*25;
        if ((Gs[s][v] >> i) & 1u) val = dv[s][v]*dv[s][i];
      }
      Ay[idx] = (_Float16)val;
    }
    // W2[o][v][c]: s=0 identity + s>=2 diagonal corrections, BN-folded
    for (int i = tid; i < 96*32; i += 256) {
      int o = i>>5, v = i&31;
      f32x4 w4 = {0.f,0.f,0.f,0.f};
      if (v < 25) {
        float inv = g1[o] / sqrtf(va1[o] + 1e-5f);
        #pragma unroll
        for (int c = 0; c < 3; ++c) {
          float acc = mlp_w[o*18 + c];          // s = 0 (A_0 = I)
          #pragma unroll
          for (int s = 2; s <= 5; ++s) {
            float t = dv[s][v];
            acc += mlp_w[o*18 + s*3 + c] * t * t;
          }
          w4[c] = acc * inv;
        }
      }
      *(f32x4*)(W2 + i*4) = w4;
    }
  }

  int gidx = blockIdx.x*256 + tid;
  int total = gridDim.x*256;
  // Wh rows kz' = (s-1)*3+c for s=1..5: 15 used, pad to 32
  for (int i = gidx; i < 96*32; i += total) {
    int o = i>>5, k = i&31;
    float inv = g1[o] / sqrtf(va1[o] + 1e-5f);
    Wh[i] = (_Float16)((k < 15) ? mlp_w[o*18 + 3 + k]*inv : 0.0f);
  }
  for (int i = gidx; i < 6*12*96*8; i += total) {
    int ch = i / 9216;
    int r  = i % 9216;
    int kc = r / 768;
    int r2 = r % 768;
    int m16 = r2 >> 3, j = r2 & 7;
    int k2 = kc*8 + j;            // k2 = wq*16 + cl
    float val = 0.f;
    if (k2 < 80) {
      int wq = k2 >> 4, cl = k2 & 15;
      int c = ch*16 + cl;
      float inv2 = g2[m16] / sqrtf(va2[m16] + 1e-5f);
      val = out_w[(m16*96 + c)*5 + wq] * inv2;
    }
    OWc[i] = (_Float16)val;
  }
  for (int i = gidx; i < 96; i += total) {
    float inv = g1[i] / sqrtf(va1[i] + 1e-5f);
    bp[i] = mlp_b[i]*inv + be1[i] - mu1[i]*inv;
    float inv2 = g2[i] / sqrtf(va2[i] + 1e-5f);
    ob[i] = out_b[i]*inv2 + be2[i] - mu2[i]*inv2;
  }
}

// LDS layout (bytes)
#define Y2_OFF 0        // f16 [2][128][8]   y2[kc][col3=tl*32+v][j], kz'=(s-1)*3+c (15 used, zero-padded)
#define HB_OFF 4096     // f16 [10][128][8]  h chunks, col2 = tl*25+v (kc>=10 via zero strip)
#define XW_OFF 24576    // f16 [16][136]     xw[col=(c*4+tl)][u=w*25+v]
#define XS_OFF 28928    // f16 [16][40]      xs[col][i] window sums
#define ZP_OFF 30208    // f16 zero strip (16 B)
#define SM_BYTES 30224

__global__ __launch_bounds__(256, 4) void msg3d_main(const float* __restrict__ x,
    const char* __restrict__ ws, float* __restrict__ out) {
  __shared__ __align__(16) char smem[SM_BYTES];
  _Float16* y2 = (_Float16*)(smem + Y2_OFF);
  _Float16* hB = (_Float16*)(smem + HB_OFF);
  _Float16* xw = (_Float16*)(smem + XW_OFF);
  _Float16* xs = (_Float16*)(smem + XS_OFF);
  _Float16* zp = (_Float16*)(smem + ZP_OFF);

  const int tid = threadIdx.x;
  const int wid = tid>>6, lane = tid&63, quad = lane>>4, l16 = lane&15;
  const int n = blockIdx.x / NT, t0 = (blockIdx.x % NT)*TB;
  const _Float16* AyG = (const _Float16*)(ws + AY_OFF);
  const _Float16* WhG = (const _Float16*)(ws + WH_OFF);
  const _Float16* OWG = (const _Float16*)(ws + OWC_OFF);
  const float* bpG  = (const float*)(ws + BP_OFF);
  const float* obG  = (const float*)(ws + OB_OFF);
  const float* W2G  = (const float*)(ws + W2_OFF);
  const f32x4 fzero = {0.f,0.f,0.f,0.f};

  // P0: stage xw; zero y2 fully (guarantees no NaN in padded K rows/cols)
  for (int i = tid; i < 2048; i += 256) {
    int col = i>>7, u = i&127;
    float val = 0.f;
    if (col < 12 && u < 125) {
      int c = col>>2, tt = col&3;
      int w = u/25, v = u - w*25;
      int fr = t0 + tt + w - 2;
      if (fr >= 0 && fr < T_F) val = x[((n*3+c)*T_F + fr)*25 + v];
    }
    xw[col*136 + u] = (_Float16)val;
  }
  *(f32x4*)(y2 + tid*8) = fzero;
  if (tid == 0) *(f32x4*)zp = fzero;
  __syncthreads();

  // P1: xs[col][i] = sum_w xw[col][w*25+i]  (f32 accumulate, f16 store; pad i 25..31 = 0)
  for (int i = tid; i < 512; i += 256) {
    int col = i>>5, k = i&31;
    float val = 0.f;
    if (k < 25) {
      float a = 0.f;
      #pragma unroll
      for (int w = 0; w < 5; ++w) a += (float)xw[col*136 + w*25 + k];
      val = a;
    }
    xs[col*40 + k] = (_Float16)val;
  }
  __syncthreads();

  // y-GEMM: y[(s,v)][(c,tl)] = sum_i Ay[(s,v)][i] * xs[(c,tl)][i]  (M=128, N=16, K=32)
  // Epilogue writes y2[kz'=(s-1)*3+c][tl*32+v] — NO w-broadcast (h_y is w-independent).
  {
    const int m0 = wid*2;
    f16x8 bx = *(f16x8*)(xs + l16*40 + quad*8);
    f16x8 a0 = *(const f16x8*)(AyG + (quad*128 + m0*16 + l16)*8);
    f16x8 a1 = *(const f16x8*)(AyG + (quad*128 + m0*16 + 16 + l16)*8);
    f32x4 y0 = __builtin_amdgcn_mfma_f32_16x16x32_f16(a0, bx, fzero, 0, 0, 0);
    f32x4 y1 = __builtin_amdgcn_mfma_f32_16x16x32_f16(a1, bx, fzero, 0, 0, 0);
    if (l16 < 12) {
      int c = l16>>2, tt = l16&3;
      #pragma unroll
      for (int half = 0; half < 2; ++half) {
        f32x4 zz = half ? y1 : y0;
        int mt = m0 + half;
        #pragma unroll
        for (int r = 0; r < 4; ++r) {
          int m = mt*16 + quad*4 + r;
          if (m < 125) {
            int s1 = m/25;                 // 0..4  <->  s = 1..5
            int v  = m - s1*25;
            int kzp = s1*3 + c;            // 0..14
            y2[((kzp>>3)*128 + tt*32 + v)*8 + (kzp&7)] = (_Float16)zz[r];
          }
        }
      }
    }
  }

  // Hoist per-lane xw values for the diag term: this lane owns cols (tl=wid, v=l16) and (tl=wid, v=l16+16),
  // reused across all 6 chunks.
  const int tl = wid;
  float xa[5][3], xb[5][3];
  {
    const int va = l16, vb = l16 + 16;
    #pragma unroll
    for (int w = 0; w < 5; ++w)
      #pragma unroll
      for (int c = 0; c < 3; ++c) {
        xa[w][c] = (float)xw[(c*4+tl)*136 + w*25 + va];
        xb[w][c] = (vb < 25) ? (float)xw[(c*4+tl)*136 + w*25 + vb] : 0.f;
      }
  }
  __syncthreads();

  // cacc initialized with the folded output bias (saves epilogue adds)
  f32x4 cacc[6][2];
  #pragma unroll
  for (int m = 0; m < 6; ++m) {
    f32x4 ob4 = *(const f32x4*)(obG + m*16 + quad*4);
    cacc[m][0] = ob4; cacc[m][1] = ob4;
  }

  // Per c-chunk: P2 h = Wh@y2 (+ per-v diag via W2, +bias, ReLU) -> hB;  P3 C += OW @ hB
  for (int ch = 0; ch < 6; ++ch) {
    f16x8 wa = *(const f16x8*)(WhG + (ch*16 + l16)*32 + quad*8);
    f32x4 bp4 = *(const f32x4*)(bpG + ch*16 + quad*4);
    const float* w2base = W2G + (ch*16 + quad*4)*128;   // o-stride = 32*4 floats

    #pragma unroll
    for (int nn = 0; nn < 2; ++nn) {
      int col3 = wid*32 + nn*16 + l16;
      const _Float16* zsrc = (quad < 2) ? (y2 + (quad*128 + col3)*8) : zp;
      f16x8 zb = *(f16x8*)zsrc;
      f32x4 hc = __builtin_amdgcn_mfma_f32_16x16x32_f16(wa, zb, fzero, 0, 0, 0);
      int v = nn*16 + l16;
      if (v < 25) {
        int col2 = tl*25 + v;
        float hyb[4];
        #pragma unroll
        for (int r = 0; r < 4; ++r) hyb[r] = hc[r] + bp4[r];
        f32x4 w2[4];
        #pragma unroll
        for (int r = 0; r < 4; ++r) w2[r] = *(const f32x4*)(w2base + r*128 + v*4);
        #pragma unroll
        for (int wq = 0; wq < 5; ++wq) {
          float x0 = nn ? xb[wq][0] : xa[wq][0];
          float x1 = nn ? xb[wq][1] : xa[wq][1];
          float x2 = nn ? xb[wq][2] : xa[wq][2];
          f16x4 hv;
          #pragma unroll
          for (int r = 0; r < 4; ++r) {
            float h = hyb[r] + w2[r][0]*x0 + w2[r][1]*x1 + w2[r][2]*x2;
            hv[r] = (_Float16)(h > 0.0f ? h : 0.0f);
          }
          int k2b = wq*16 + quad*4;
          *(f16x4*)(hB + ((k2b>>3)*128 + col2)*8 + (k2b&7)) = hv;
        }
      }
    }
    __syncthreads();

    #pragma unroll
    for (int kt = 0; kt < 3; ++kt) {
      int kc = kt*4 + quad;
      int col0 = wid*32 + l16;
      const _Float16* h0 = (kc < 10) ? (hB + (kc*128 + col0)*8)      : zp;
      const _Float16* h1 = (kc < 10) ? (hB + (kc*128 + col0 + 16)*8) : zp;
      f16x8 b0 = *(f16x8*)h0;
      f16x8 b1 = *(f16x8*)h1;
      #pragma unroll
      for (int m = 0; m < 6; ++m) {
        f16x8 a = *(const f16x8*)(OWG + ((ch*12 + kc)*96 + m*16 + l16)*8);
        cacc[m][0] = __builtin_amdgcn_mfma_f32_16x16x32_f16(a, b0, cacc[m][0], 0, 0, 0);
        cacc[m][1] = __builtin_amdgcn_mfma_f32_16x16x32_f16(a, b1, cacc[m][1], 0, 0, 0);
      }
    }
    __syncthreads();
  }

  // Epilogue (bias already in cacc)
  #pragma unroll
  for (int nn = 0; nn < 2; ++nn) {
    int col2 = (wid*2 + nn)*16 + l16;
    if (col2 < 100) {
      int tte = col2 / 25, v = col2 - tte*25;
      #pragma unroll
      for (int m = 0; m < 6; ++m) {
        #pragma unroll
        for (int r = 0; r < 4; ++r) {
          int o2 = m*16 + quad*4 + r;
          out[((n*96 + o2)*T_F + t0 + tte)*25 + v] = cacc[m][nn][r];
        }
      }
    }
  }
}

extern "C" void kernel_launch(void* const* d_in, const int* in_sizes, int n_in,
                              void* d_out, int out_size, void* d_ws, size_t ws_size,
                              hipStream_t stream) {
  const float* x     = (const float*)d_in[0];
  const float* mlp_w = (const float*)d_in[1];
  const float* mlp_b = (const float*)d_in[2];
  const float* g1    = (const float*)d_in[3];
  const float* be1   = (const float*)d_in[4];
  const float* mu1   = (const float*)d_in[5];
  const float* va1   = (const float*)d_in[6];
  const float* out_w = (const float*)d_in[7];
  const float* out_b = (const float*)d_in[8];
  const float* g2    = (const float*)d_in[9];
  const float* be2   = (const float*)d_in[10];
  const float* mu2   = (const float*)d_in[11];
  const float* va2   = (const float*)d_in[12];
  float* out = (float*)d_out;
  char*  ws  = (char*)d_ws;

  setup_kernel<<<64, 256, 0, stream>>>(mlp_w, mlp_b, g1, be1, mu1, va1,
                                       out_w, out_b, g2, be2, mu2, va2, ws);
  msg3d_main<<<N_B * NT, 256, 0, stream>>>(x, ws, out);
}

// Round 2
// 393.804 us; speedup vs baseline: 1.4469x; 1.4469x over previous
//
#include <hip/hip_runtime.h>

typedef __attribute__((ext_vector_type(8))) _Float16 f16x8;
typedef __attribute__((ext_vector_type(4))) _Float16 f16x4;
typedef __attribute__((ext_vector_type(4))) float f32x4;

#define N_B 64
#define T_F 300
#define TB 4
#define NT (T_F/TB)

// ws byte offsets
#define AY_OFF  0        // f16 [4][128][8]    y-GEMM A operand, K-chunked
#define WH_OFF  8192     // f16 [96][32]       folded mlp weight; k=0..14: Wh[(s-1)*3+c], k=15: folded bias
#define OWC_OFF 14336    // f16 [6][12][96][8] folded out weight, chunked
#define BP_OFF  124928   // float[96]          (unused by main now; kept for layout stability)
#define OB_OFF  125312   // float[96]
#define W2_OFF  125696   // float[96][32][4]   diag weights W2[o][v][c] (c<3 used)

__device__ __constant__ int EDGES[24][2] = {
  {1,2},{2,21},{3,21},{4,3},{5,21},{6,5},{7,6},{8,7},{9,21},{10,9},{11,10},{12,11},
  {13,1},{14,13},{15,14},{16,15},{17,1},{18,17},{19,18},{20,19},{22,23},{23,8},{24,25},{25,12}
};

__global__ void setup_kernel(const float* __restrict__ mlp_w, const float* __restrict__ mlp_b,
    const float* __restrict__ g1, const float* __restrict__ be1,
    const float* __restrict__ mu1, const float* __restrict__ va1,
    const float* __restrict__ out_w, const float* __restrict__ out_b,
    const float* __restrict__ g2, const float* __restrict__ be2,
    const float* __restrict__ mu2, const float* __restrict__ va2,
    char* __restrict__ wsb) {
  _Float16* Ay  = (_Float16*)(wsb + AY_OFF);
  _Float16* Wh  = (_Float16*)(wsb + WH_OFF);
  _Float16* OWc = (_Float16*)(wsb + OWC_OFF);
  float* bp  = (float*)(wsb + BP_OFF);
  float* ob  = (float*)(wsb + OB_OFF);
  float* W2  = (float*)(wsb + W2_OFF);
  int tid = threadIdx.x;

  if (blockIdx.x == 0) {
    // A_large = J5 (x) B with B = A+I  =>  scale s reduces to 25-node graph:
    //   s=0: A_s = I;  s=1: M = J(x)B;  s>=2: M = J(x)(R_s\R_{s-1}) + I.
    __shared__ unsigned int Rk[6][25];
    __shared__ unsigned int Gs[6][25];
    __shared__ float dv[6][25];
    if (tid < 25) {
      unsigned int m = 1u << tid;
      for (int e = 0; e < 24; ++e) {
        int a = EDGES[e][0]-1, b = EDGES[e][1]-1;
        if (a == tid) m |= 1u<<b;
        if (b == tid) m |= 1u<<a;
      }
      Gs[1][tid] = m;   // B masks (incl. self)
      Rk[1][tid] = m;
    }
    __syncthreads();
    for (int k = 2; k <= 5; ++k) {
      if (tid < 25) {
        unsigned int p = Rk[k-1][tid], nm = p;
        for (int j = 0; j < 25; ++j) if ((p>>j)&1u) nm |= Gs[1][j];
        Rk[k][tid] = nm;
      }
      __syncthreads();
    }
    if (tid < 25) {
      for (int s = 1; s <= 5; ++s) {
        unsigned int g = (s==1) ? Gs[1][tid] : (Rk[s][tid] & ~Rk[s-1][tid]);
        if (s >= 2) Gs[s][tid] = g;
        int d = 5*__popc(g) + ((s>=2)?1:0);
        dv[s][tid] = (d>0) ? (float)(1.0/sqrt((double)d)) : 0.0f;
      }
    }
    __syncthreads();
    // Ay: [kc=0..3][row=0..127][j=0..7], row=(s-1)*25+v for s=1..5, i = kc*8+j
    for (int idx = tid; idx < 4096; idx += 256) {
      int kc = idx >> 10, row = (idx>>3)&127, j = idx&7;
      int i = kc*8 + j;
      float val = 0.f;
      if (row < 125 && i < 25) {
        int s = 1 + row/25, v = row - (s-1)*25;
        if ((Gs[s][v] >> i) & 1u) val = dv[s][v]*dv[s][i];
      }
      Ay[idx] = (_Float16)val;
    }
    // W2[o][v][c]: s=0 identity + s>=2 diagonal corrections, BN-folded
    for (int i = tid; i < 96*32; i += 256) {
      int o = i>>5, v = i&31;
      f32x4 w4 = {0.f,0.f,0.f,0.f};
      if (v < 25) {
        float inv = g1[o] / sqrtf(va1[o] + 1e-5f);
        #pragma unroll
        for (int c = 0; c < 3; ++c) {
          float acc = mlp_w[o*18 + c];          // s = 0 (A_0 = I)
          #pragma unroll
          for (int s = 2; s <= 5; ++s) {
            float t = dv[s][v];
            acc += mlp_w[o*18 + s*3 + c] * t * t;
          }
          w4[c] = acc * inv;
        }
      }
      *(f32x4*)(W2 + i*4) = w4;
    }
  }

  int gidx = blockIdx.x*256 + tid;
  int total = gridDim.x*256;
  // Wh rows k = (s-1)*3+c for s=1..5 (15 used); k=15 holds the folded bias (paired
  // with a constant-1.0 row in y2) so P2's MFMA produces h_y + bias directly.
  for (int i = gidx; i < 96*32; i += total) {
    int o = i>>5, k = i&31;
    float inv = g1[o] / sqrtf(va1[o] + 1e-5f);
    float val = 0.f;
    if (k < 15)      val = mlp_w[o*18 + 3 + k]*inv;
    else if (k == 15) val = mlp_b[o]*inv + be1[o] - mu1[o]*inv;
    Wh[i] = (_Float16)val;
  }
  for (int i = gidx; i < 6*12*96*8; i += total) {
    int ch = i / 9216;
    int r  = i % 9216;
    int kc = r / 768;
    int r2 = r % 768;
    int m16 = r2 >> 3, j = r2 & 7;
    int k2 = kc*8 + j;            // k2 = wq*16 + cl
    float val = 0.f;
    if (k2 < 80) {
      int wq = k2 >> 4, cl = k2 & 15;
      int c = ch*16 + cl;
      float inv2 = g2[m16] / sqrtf(va2[m16] + 1e-5f);
      val = out_w[(m16*96 + c)*5 + wq] * inv2;
    }
    OWc[i] = (_Float16)val;
  }
  for (int i = gidx; i < 96; i += total) {
    float inv = g1[i] / sqrtf(va1[i] + 1e-5f);
    bp[i] = mlp_b[i]*inv + be1[i] - mu1[i]*inv;
    float inv2 = g2[i] / sqrtf(va2[i] + 1e-5f);
    ob[i] = out_b[i]*inv2 + be2[i] - mu2[i]*inv2;
  }
}

// LDS layout (bytes)
#define Y2_OFF 0        // f16 [2][128][8]   y2[kc][col3=tl*32+v][j], kz'=(s-1)*3+c (15 used; row 15 = 1.0)
#define HB_OFF 4096     // f16 [10][128][8]  h chunks, col2 = tl*25+v (kc>=10 via zero strip)
#define XW_OFF 24576    // f16 [16][136]     xw[col=(c*4+tl)][u=w*25+v]
#define XS_OFF 28928    // f16 [16][40]      xs[col][i] window sums
#define ZP_OFF 30208    // f16 zero strip (16 B)
#define SM_BYTES 30224

// bounds (256,3): round 1's (256,4) forced vgpr+agpr <= 128 and the allocator
// spilled to scratch (FETCH 9MB->394MB, VGPR_Count=64 cap signature). 3 waves/EU
// gives ~170 regs of headroom; if actual usage lands <=128 runtime still gets 4 blocks/CU.
__global__ __launch_bounds__(256, 3) void msg3d_main(const float* __restrict__ x,
    const char* __restrict__ ws, float* __restrict__ out) {
  __shared__ __align__(16) char smem[SM_BYTES];
  _Float16* y2 = (_Float16*)(smem + Y2_OFF);
  _Float16* hB = (_Float16*)(smem + HB_OFF);
  _Float16* xw = (_Float16*)(smem + XW_OFF);
  _Float16* xs = (_Float16*)(smem + XS_OFF);
  _Float16* zp = (_Float16*)(smem + ZP_OFF);

  const int tid = threadIdx.x;
  const int wid = tid>>6, lane = tid&63, quad = lane>>4, l16 = lane&15;
  const int n = blockIdx.x / NT, t0 = (blockIdx.x % NT)*TB;
  const _Float16* AyG = (const _Float16*)(ws + AY_OFF);
  const _Float16* WhG = (const _Float16*)(ws + WH_OFF);
  const _Float16* OWG = (const _Float16*)(ws + OWC_OFF);
  const float* obG  = (const float*)(ws + OB_OFF);
  const float* W2G  = (const float*)(ws + W2_OFF);
  const f32x4 fzero = {0.f,0.f,0.f,0.f};

  // P0: stage xw; zero y2; plant the constant-1.0 bias row (kz'=15 -> kc=1, j=7)
  for (int i = tid; i < 2048; i += 256) {
    int col = i>>7, u = i&127;
    float val = 0.f;
    if (col < 12 && u < 125) {
      int c = col>>2, tt = col&3;
      int w = u/25, v = u - w*25;
      int fr = t0 + tt + w - 2;
      if (fr >= 0 && fr < T_F) val = x[((n*3+c)*T_F + fr)*25 + v];
    }
    xw[col*136 + u] = (_Float16)val;
  }
  *(f32x4*)(y2 + tid*8) = fzero;
  if (tid >= 128) y2[tid*8 + 7] = (_Float16)1.0f;   // row kz'=15 == 1.0 for every col
  if (tid == 0) *(f32x4*)zp = fzero;
  __syncthreads();

  // P1: xs[col][i] = sum_w xw[col][w*25+i]  (f32 accumulate, f16 store; pad i 25..31 = 0)
  for (int i = tid; i < 512; i += 256) {
    int col = i>>5, k = i&31;
    float val = 0.f;
    if (k < 25) {
      float a = 0.f;
      #pragma unroll
      for (int w = 0; w < 5; ++w) a += (float)xw[col*136 + w*25 + k];
      val = a;
    }
    xs[col*40 + k] = (_Float16)val;
  }
  __syncthreads();

  // y-GEMM: y[(s,v)][(c,tl)] = sum_i Ay[(s,v)][i] * xs[(c,tl)][i]  (M=128, N=16, K=32)
  // Epilogue writes y2[kz'=(s-1)*3+c][tl*32+v] — no w-broadcast (h_y is w-independent).
  {
    const int m0 = wid*2;
    f16x8 bx = *(f16x8*)(xs + l16*40 + quad*8);
    f16x8 a0 = *(const f16x8*)(AyG + (quad*128 + m0*16 + l16)*8);
    f16x8 a1 = *(const f16x8*)(AyG + (quad*128 + m0*16 + 16 + l16)*8);
    f32x4 y0 = __builtin_amdgcn_mfma_f32_16x16x32_f16(a0, bx, fzero, 0, 0, 0);
    f32x4 y1 = __builtin_amdgcn_mfma_f32_16x16x32_f16(a1, bx, fzero, 0, 0, 0);
    if (l16 < 12) {
      int c = l16>>2, tt = l16&3;
      #pragma unroll
      for (int half = 0; half < 2; ++half) {
        f32x4 zz = half ? y1 : y0;
        int mt = m0 + half;
        #pragma unroll
        for (int r = 0; r < 4; ++r) {
          int m = mt*16 + quad*4 + r;
          if (m < 125) {
            int s1 = m/25;                 // 0..4  <->  s = 1..5
            int v  = m - s1*25;
            int kzp = s1*3 + c;            // 0..14
            y2[((kzp>>3)*128 + tt*32 + v)*8 + (kzp&7)] = (_Float16)zz[r];
          }
        }
      }
    }
  }

  // Hoist ONLY the nn=0 per-lane xw values (v=l16<16): 15 regs. The nn=1 half
  // (9 active lanes) reads xw from LDS at use — trades 15 regs for cheap ds_reads.
  const int tl = wid;
  float xa[5][3];
  #pragma unroll
  for (int w = 0; w < 5; ++w)
    #pragma unroll
    for (int c = 0; c < 3; ++c)
      xa[w][c] = (float)xw[(c*4+tl)*136 + w*25 + l16];
  __syncthreads();

  // cacc initialized with the folded output bias (saves epilogue adds)
  f32x4 cacc[6][2];
  #pragma unroll
  for (int m = 0; m < 6; ++m) {
    f32x4 ob4 = *(const f32x4*)(obG + m*16 + quad*4);
    cacc[m][0] = ob4; cacc[m][1] = ob4;
  }

  // Per c-chunk: P2 h = Wh@y2 (bias via K-row 15; + per-v diag via W2; ReLU) -> hB;
  //              P3 C += OW @ hB
  for (int ch = 0; ch < 6; ++ch) {
    f16x8 wa = *(const f16x8*)(WhG + (ch*16 + l16)*32 + quad*8);
    const float* w2base = W2G + (ch*16 + quad*4)*128;   // o-stride = 32*4 floats

    #pragma unroll
    for (int nn = 0; nn < 2; ++nn) {
      int col3 = wid*32 + nn*16 + l16;
      const _Float16* zsrc = (quad < 2) ? (y2 + (quad*128 + col3)*8) : zp;
      f16x8 zb = *(f16x8*)zsrc;
      f32x4 hc = __builtin_amdgcn_mfma_f32_16x16x32_f16(wa, zb, fzero, 0, 0, 0);
      int v = nn*16 + l16;
      if (v < 25) {
        int col2 = tl*25 + v;
        f32x4 w2[4];
        #pragma unroll
        for (int r = 0; r < 4; ++r) w2[r] = *(const f32x4*)(w2base + r*128 + v*4);
        #pragma unroll
        for (int wq = 0; wq < 5; ++wq) {
          float x0, x1, x2;
          if (nn == 0) { x0 = xa[wq][0]; x1 = xa[wq][1]; x2 = xa[wq][2]; }
          else {
            x0 = (float)xw[(0*4+tl)*136 + wq*25 + v];
            x1 = (float)xw[(1*4+tl)*136 + wq*25 + v];
            x2 = (float)xw[(2*4+tl)*136 + wq*25 + v];
          }
          f16x4 hv;
          #pragma unroll
          for (int r = 0; r < 4; ++r) {
            float h = hc[r] + w2[r][0]*x0 + w2[r][1]*x1 + w2[r][2]*x2;
            hv[r] = (_Float16)(h > 0.0f ? h : 0.0f);
          }
          int k2b = wq*16 + quad*4;
          *(f16x4*)(hB + ((k2b>>3)*128 + col2)*8 + (k2b&7)) = hv;
        }
      }
    }
    __syncthreads();

    #pragma unroll
    for (int kt = 0; kt < 3; ++kt) {
      int kc = kt*4 + quad;
      int col0 = wid*32 + l16;
      const _Float16* h0 = (kc < 10) ? (hB + (kc*128 + col0)*8)      : zp;
      const _Float16* h1 = (kc < 10) ? (hB + (kc*128 + col0 + 16)*8) : zp;
      f16x8 b0 = *(f16x8*)h0;
      f16x8 b1 = *(f16x8*)h1;
      #pragma unroll
      for (int m = 0; m < 6; ++m) {
        f16x8 a = *(const f16x8*)(OWG + ((ch*12 + kc)*96 + m*16 + l16)*8);
        cacc[m][0] = __builtin_amdgcn_mfma_f32_16x16x32_f16(a, b0, cacc[m][0], 0, 0, 0);
        cacc[m][1] = __builtin_amdgcn_mfma_f32_16x16x32_f16(a, b1, cacc[m][1], 0, 0, 0);
      }
    }
    __syncthreads();
  }

  // Epilogue (bias already in cacc)
  #pragma unroll
  for (int nn = 0; nn < 2; ++nn) {
    int col2 = (wid*2 + nn)*16 + l16;
    if (col2 < 100) {
      int tte = col2 / 25, v = col2 - tte*25;
      #pragma unroll
      for (int m = 0; m < 6; ++m) {
        #pragma unroll
        for (int r = 0; r < 4; ++r) {
          int o2 = m*16 + quad*4 + r;
          out[((n*96 + o2)*T_F + t0 + tte)*25 + v] = cacc[m][nn][r];
        }
      }
    }
  }
}

extern "C" void kernel_launch(void* const* d_in, const int* in_sizes, int n_in,
                              void* d_out, int out_size, void* d_ws, size_t ws_size,
                              hipStream_t stream) {
  const float* x     = (const float*)d_in[0];
  const float* mlp_w = (const float*)d_in[1];
  const float* mlp_b = (const float*)d_in[2];
  const float* g1    = (const float*)d_in[3];
  const float* be1   = (const float*)d_in[4];
  const float* mu1   = (const float*)d_in[5];
  const float* va1   = (const float*)d_in[6];
  const float* out_w = (const float*)d_in[7];
  const float* out_b = (const float*)d_in[8];
  const float* g2    = (const float*)d_in[9];
  const float* be2   = (const float*)d_in[10];
  const float* mu2   = (const float*)d_in[11];
  const float* va2   = (const float*)d_in[12];
  float* out = (float*)d_out;
  char*  ws  = (char*)d_ws;

  setup_kernel<<<64, 256, 0, stream>>>(mlp_w, mlp_b, g1, be1, mu1, va1,
                                       out_w, out_b, g2, be2, mu2, va2, ws);
  msg3d_main<<<N_B * NT, 256, 0, stream>>>(x, ws, out);
}

// Round 3
// 387.283 us; speedup vs baseline: 1.4712x; 1.0168x over previous
//
#include <hip/hip_runtime.h>

typedef __attribute__((ext_vector_type(8))) _Float16 f16x8;
typedef __attribute__((ext_vector_type(4))) _Float16 f16x4;
typedef __attribute__((ext_vector_type(4))) float f32x4;

#define N_B 64
#define T_F 300
#define TB 4
#define NT (T_F/TB)

// ws byte offsets
#define AY_OFF  0        // f16 [4][128][8]    y-GEMM A operand, K-chunked
#define WH_OFF  8192     // f16 [96][32]       folded mlp weight; k=0..14: Wh[(s-1)*3+c], k=15: folded bias
#define OWC_OFF 14336    // f16 [6][12][96][8] folded out weight, chunked
#define BP_OFF  124928   // float[96]          (unused by main now; kept for layout stability)
#define OB_OFF  125312   // float[96]
#define W2_OFF  125696   // float[96][32][4]   diag weights W2[o][v][c] (c<3 used)

__device__ __constant__ int EDGES[24][2] = {
  {1,2},{2,21},{3,21},{4,3},{5,21},{6,5},{7,6},{8,7},{9,21},{10,9},{11,10},{12,11},
  {13,1},{14,13},{15,14},{16,15},{17,1},{18,17},{19,18},{20,19},{22,23},{23,8},{24,25},{25,12}
};

__global__ void setup_kernel(const float* __restrict__ mlp_w, const float* __restrict__ mlp_b,
    const float* __restrict__ g1, const float* __restrict__ be1,
    const float* __restrict__ mu1, const float* __restrict__ va1,
    const float* __restrict__ out_w, const float* __restrict__ out_b,
    const float* __restrict__ g2, const float* __restrict__ be2,
    const float* __restrict__ mu2, const float* __restrict__ va2,
    char* __restrict__ wsb) {
  _Float16* Ay  = (_Float16*)(wsb + AY_OFF);
  _Float16* Wh  = (_Float16*)(wsb + WH_OFF);
  _Float16* OWc = (_Float16*)(wsb + OWC_OFF);
  float* bp  = (float*)(wsb + BP_OFF);
  float* ob  = (float*)(wsb + OB_OFF);
  float* W2  = (float*)(wsb + W2_OFF);
  int tid = threadIdx.x;

  if (blockIdx.x == 0) {
    // A_large = J5 (x) B with B = A+I  =>  scale s reduces to 25-node graph:
    //   s=0: A_s = I;  s=1: M = J(x)B;  s>=2: M = J(x)(R_s\R_{s-1}) + I.
    __shared__ unsigned int Rk[6][25];
    __shared__ unsigned int Gs[6][25];
    __shared__ float dv[6][25];
    if (tid < 25) {
      unsigned int m = 1u << tid;
      for (int e = 0; e < 24; ++e) {
        int a = EDGES[e][0]-1, b = EDGES[e][1]-1;
        if (a == tid) m |= 1u<<b;
        if (b == tid) m |= 1u<<a;
      }
      Gs[1][tid] = m;   // B masks (incl. self)
      Rk[1][tid] = m;
    }
    __syncthreads();
    for (int k = 2; k <= 5; ++k) {
      if (tid < 25) {
        unsigned int p = Rk[k-1][tid], nm = p;
        for (int j = 0; j < 25; ++j) if ((p>>j)&1u) nm |= Gs[1][j];
        Rk[k][tid] = nm;
      }
      __syncthreads();
    }
    if (tid < 25) {
      for (int s = 1; s <= 5; ++s) {
        unsigned int g = (s==1) ? Gs[1][tid] : (Rk[s][tid] & ~Rk[s-1][tid]);
        if (s >= 2) Gs[s][tid] = g;
        int d = 5*__popc(g) + ((s>=2)?1:0);
        dv[s][tid] = (d>0) ? (float)(1.0/sqrt((double)d)) : 0.0f;
      }
    }
    __syncthreads();
    // Ay: [kc=0..3][row=0..127][j=0..7], row=(s-1)*25+v for s=1..5, i = kc*8+j
    for (int idx = tid; idx < 4096; idx += 256) {
      int kc = idx >> 10, row = (idx>>3)&127, j = idx&7;
      int i = kc*8 + j;
      float val = 0.f;
      if (row < 125 && i < 25) {
        int s = 1 + row/25, v = row - (s-1)*25;
        if ((Gs[s][v] >> i) & 1u) val = dv[s][v]*dv[s][i];
      }
      Ay[idx] = (_Float16)val;
    }
    // W2[o][v][c]: s=0 identity + s>=2 diagonal corrections, BN-folded
    for (int i = tid; i < 96*32; i += 256) {
      int o = i>>5, v = i&31;
      f32x4 w4 = {0.f,0.f,0.f,0.f};
      if (v < 25) {
        float inv = g1[o] / sqrtf(va1[o] + 1e-5f);
        #pragma unroll
        for (int c = 0; c < 3; ++c) {
          float acc = mlp_w[o*18 + c];          // s = 0 (A_0 = I)
          #pragma unroll
          for (int s = 2; s <= 5; ++s) {
            float t = dv[s][v];
            acc += mlp_w[o*18 + s*3 + c] * t * t;
          }
          w4[c] = acc * inv;
        }
      }
      *(f32x4*)(W2 + i*4) = w4;
    }
  }

  int gidx = blockIdx.x*256 + tid;
  int total = gridDim.x*256;
  // Wh rows k = (s-1)*3+c for s=1..5 (15 used); k=15 holds the folded bias (paired
  // with a constant-1.0 row in y2) so P2's MFMA produces h_y + bias directly.
  for (int i = gidx; i < 96*32; i += total) {
    int o = i>>5, k = i&31;
    float inv = g1[o] / sqrtf(va1[o] + 1e-5f);
    float val = 0.f;
    if (k < 15)      val = mlp_w[o*18 + 3 + k]*inv;
    else if (k == 15) val = mlp_b[o]*inv + be1[o] - mu1[o]*inv;
    Wh[i] = (_Float16)val;
  }
  for (int i = gidx; i < 6*12*96*8; i += total) {
    int ch = i / 9216;
    int r  = i % 9216;
    int kc = r / 768;
    int r2 = r % 768;
    int m16 = r2 >> 3, j = r2 & 7;
    int k2 = kc*8 + j;            // k2 = wq*16 + cl
    float val = 0.f;
    if (k2 < 80) {
      int wq = k2 >> 4, cl = k2 & 15;
      int c = ch*16 + cl;
      float inv2 = g2[m16] / sqrtf(va2[m16] + 1e-5f);
      val = out_w[(m16*96 + c)*5 + wq] * inv2;
    }
    OWc[i] = (_Float16)val;
  }
  for (int i = gidx; i < 96; i += total) {
    float inv = g1[i] / sqrtf(va1[i] + 1e-5f);
    bp[i] = mlp_b[i]*inv + be1[i] - mu1[i]*inv;
    float inv2 = g2[i] / sqrtf(va2[i] + 1e-5f);
    ob[i] = out_b[i]*inv2 + be2[i] - mu2[i]*inv2;
  }
}

// LDS layout (bytes)
#define Y2_OFF 0        // f16 [2][128][8]   y2[kc][col3=tl*32+v][j], kz'=(s-1)*3+c (15 used; row 15 = 1.0)
#define HB_OFF 4096     // f16 [10][128][8]  h chunks, col2 = tl*32+v  (PER-WAVE 32-col slices!)
#define XW_OFF 24576    // f16 [16][136]     xw[col=(c*4+tl)][u=w*25+v]
#define XS_OFF 28928    // f16 [16][40]      xs[col][i] window sums
#define ZP_OFF 30208    // f16 zero strip (16 B)
#define SM_BYTES 30224

// bounds (256,3): (256,4) forced vgpr+agpr <= 128 -> scratch spills (round-1 lesson).
__global__ __launch_bounds__(256, 3) void msg3d_main(const float* __restrict__ x,
    const char* __restrict__ ws, float* __restrict__ out) {
  __shared__ __align__(16) char smem[SM_BYTES];
  _Float16* y2 = (_Float16*)(smem + Y2_OFF);
  _Float16* hB = (_Float16*)(smem + HB_OFF);
  _Float16* xw = (_Float16*)(smem + XW_OFF);
  _Float16* xs = (_Float16*)(smem + XS_OFF);
  _Float16* zp = (_Float16*)(smem + ZP_OFF);

  const int tid = threadIdx.x;
  const int wid = tid>>6, lane = tid&63, quad = lane>>4, l16 = lane&15;
  const int n = blockIdx.x / NT, t0 = (blockIdx.x % NT)*TB;
  const _Float16* AyG = (const _Float16*)(ws + AY_OFF);
  const _Float16* WhG = (const _Float16*)(ws + WH_OFF);
  const _Float16* OWG = (const _Float16*)(ws + OWC_OFF);
  const float* obG  = (const float*)(ws + OB_OFF);
  const float* W2G  = (const float*)(ws + W2_OFF);
  const f32x4 fzero = {0.f,0.f,0.f,0.f};

  // P0: stage xw; zero y2; plant the constant-1.0 bias row (kz'=15 -> kc=1, j=7)
  for (int i = tid; i < 2048; i += 256) {
    int col = i>>7, u = i&127;
    float val = 0.f;
    if (col < 12 && u < 125) {
      int c = col>>2, tt = col&3;
      int w = u/25, v = u - w*25;
      int fr = t0 + tt + w - 2;
      if (fr >= 0 && fr < T_F) val = x[((n*3+c)*T_F + fr)*25 + v];
    }
    xw[col*136 + u] = (_Float16)val;
  }
  *(f32x4*)(y2 + tid*8) = fzero;
  if (tid >= 128) y2[tid*8 + 7] = (_Float16)1.0f;   // row kz'=15 == 1.0 for every col
  if (tid == 0) *(f32x4*)zp = fzero;
  __syncthreads();

  // P1: xs[col][i] = sum_w xw[col][w*25+i]  (f32 accumulate, f16 store; pad i 25..31 = 0)
  for (int i = tid; i < 512; i += 256) {
    int col = i>>5, k = i&31;
    float val = 0.f;
    if (k < 25) {
      float a = 0.f;
      #pragma unroll
      for (int w = 0; w < 5; ++w) a += (float)xw[col*136 + w*25 + k];
      val = a;
    }
    xs[col*40 + k] = (_Float16)val;
  }
  __syncthreads();

  // y-GEMM: y[(s,v)][(c,tl)] = sum_i Ay[(s,v)][i] * xs[(c,tl)][i]  (M=128, N=16, K=32)
  // Epilogue writes y2[kz'=(s-1)*3+c][tl*32+v] — no w-broadcast (h_y is w-independent).
  {
    const int m0 = wid*2;
    f16x8 bx = *(f16x8*)(xs + l16*40 + quad*8);
    f16x8 a0 = *(const f16x8*)(AyG + (quad*128 + m0*16 + l16)*8);
    f16x8 a1 = *(const f16x8*)(AyG + (quad*128 + m0*16 + 16 + l16)*8);
    f32x4 y0 = __builtin_amdgcn_mfma_f32_16x16x32_f16(a0, bx, fzero, 0, 0, 0);
    f32x4 y1 = __builtin_amdgcn_mfma_f32_16x16x32_f16(a1, bx, fzero, 0, 0, 0);
    if (l16 < 12) {
      int c = l16>>2, tt = l16&3;
      #pragma unroll
      for (int half = 0; half < 2; ++half) {
        f32x4 zz = half ? y1 : y0;
        int mt = m0 + half;
        #pragma unroll
        for (int r = 0; r < 4; ++r) {
          int m = mt*16 + quad*4 + r;
          if (m < 125) {
            int s1 = m/25;                 // 0..4  <->  s = 1..5
            int v  = m - s1*25;
            int kzp = s1*3 + c;            // 0..14
            y2[((kzp>>3)*128 + tt*32 + v)*8 + (kzp&7)] = (_Float16)zz[r];
          }
        }
      }
    }
  }

  // Hoist ONLY the nn=0 per-lane xw values (v=l16<16): 15 regs. The nn=1 half
  // reads xw from LDS at use.
  const int tl = wid;
  float xa[5][3];
  #pragma unroll
  for (int w = 0; w < 5; ++w)
    #pragma unroll
    for (int c = 0; c < 3; ++c)
      xa[w][c] = (float)xw[(c*4+tl)*136 + w*25 + l16];
  __syncthreads();
  // ===== Last barrier. From here on each wave is fully independent: =====
  // hB col space is tl*32+v (tl=wid), so wave w writes exactly the 32-col slice
  // [32w,32w+32) that its own P3 reads. y2/xw/OW are read-only. Holes (v>=25)
  // are never written but only pollute MFMA output cols >=25, which the
  // epilogue discards (MFMA out col j depends only on B col j).

  // cacc initialized with the folded output bias (saves epilogue adds)
  f32x4 cacc[6][2];
  #pragma unroll
  for (int m = 0; m < 6; ++m) {
    f32x4 ob4 = *(const f32x4*)(obG + m*16 + quad*4);
    cacc[m][0] = ob4; cacc[m][1] = ob4;
  }

  // Per c-chunk: P2 h = Wh@y2 (bias via K-row 15; + per-v diag via W2; ReLU) -> hB;
  //              P3 C += OW @ hB.   No barriers: per-wave dataflow only.
  for (int ch = 0; ch < 6; ++ch) {
    f16x8 wa = *(const f16x8*)(WhG + (ch*16 + l16)*32 + quad*8);
    const float* w2base = W2G + (ch*16 + quad*4)*128;   // o-stride = 32*4 floats

    #pragma unroll
    for (int nn = 0; nn < 2; ++nn) {
      int col3 = wid*32 + nn*16 + l16;
      const _Float16* zsrc = (quad < 2) ? (y2 + (quad*128 + col3)*8) : zp;
      f16x8 zb = *(f16x8*)zsrc;
      f32x4 hc = __builtin_amdgcn_mfma_f32_16x16x32_f16(wa, zb, fzero, 0, 0, 0);
      int v = nn*16 + l16;
      if (v < 25) {
        int col2 = tl*32 + v;           // per-wave 32-col slice
        f32x4 w2[4];
        #pragma unroll
        for (int r = 0; r < 4; ++r) w2[r] = *(const f32x4*)(w2base + r*128 + v*4);
        #pragma unroll
        for (int wq = 0; wq < 5; ++wq) {
          float x0, x1, x2;
          if (nn == 0) { x0 = xa[wq][0]; x1 = xa[wq][1]; x2 = xa[wq][2]; }
          else {
            x0 = (float)xw[(0*4+tl)*136 + wq*25 + v];
            x1 = (float)xw[(1*4+tl)*136 + wq*25 + v];
            x2 = (float)xw[(2*4+tl)*136 + wq*25 + v];
          }
          f16x4 hv;
          #pragma unroll
          for (int r = 0; r < 4; ++r) {
            float h = hc[r] + w2[r][0]*x0 + w2[r][1]*x1 + w2[r][2]*x2;
            hv[r] = (_Float16)(h > 0.0f ? h : 0.0f);
          }
          int k2b = wq*16 + quad*4;
          *(f16x4*)(hB + ((k2b>>3)*128 + col2)*8 + (k2b&7)) = hv;
        }
      }
    }

    #pragma unroll
    for (int kt = 0; kt < 3; ++kt) {
      int kc = kt*4 + quad;
      int col0 = wid*32 + l16;
      const _Float16* h0 = (kc < 10) ? (hB + (kc*128 + col0)*8)      : zp;
      const _Float16* h1 = (kc < 10) ? (hB + (kc*128 + col0 + 16)*8) : zp;
      f16x8 b0 = *(f16x8*)h0;
      f16x8 b1 = *(f16x8*)h1;
      #pragma unroll
      for (int m = 0; m < 6; ++m) {
        f16x8 a = *(const f16x8*)(OWG + ((ch*12 + kc)*96 + m*16 + l16)*8);
        cacc[m][0] = __builtin_amdgcn_mfma_f32_16x16x32_f16(a, b0, cacc[m][0], 0, 0, 0);
        cacc[m][1] = __builtin_amdgcn_mfma_f32_16x16x32_f16(a, b1, cacc[m][1], 0, 0, 0);
      }
    }
  }

  // Epilogue (bias already in cacc). cacc col = wid*32 + nn*16 + l16 -> tte = wid, v = nn*16+l16.
  #pragma unroll
  for (int nn = 0; nn < 2; ++nn) {
    int v = nn*16 + l16;
    if (v < 25) {
      #pragma unroll
      for (int m = 0; m < 6; ++m) {
        #pragma unroll
        for (int r = 0; r < 4; ++r) {
          int o2 = m*16 + quad*4 + r;
          out[((n*96 + o2)*T_F + t0 + wid)*25 + v] = cacc[m][nn][r];
        }
      }
    }
  }
}

extern "C" void kernel_launch(void* const* d_in, const int* in_sizes, int n_in,
                              void* d_out, int out_size, void* d_ws, size_t ws_size,
                              hipStream_t stream) {
  const float* x     = (const float*)d_in[0];
  const float* mlp_w = (const float*)d_in[1];
  const float* mlp_b = (const float*)d_in[2];
  const float* g1    = (const float*)d_in[3];
  const float* be1   = (const float*)d_in[4];
  const float* mu1   = (const float*)d_in[5];
  const float* va1   = (const float*)d_in[6];
  const float* out_w = (const float*)d_in[7];
  const float* out_b = (const float*)d_in[8];
  const float* g2    = (const float*)d_in[9];
  const float* be2   = (const float*)d_in[10];
  const float* mu2   = (const float*)d_in[11];
  const float* va2   = (const float*)d_in[12];
  float* out = (float*)d_out;
  char*  ws  = (char*)d_ws;

  setup_kernel<<<64, 256, 0, stream>>>(mlp_w, mlp_b, g1, be1, mu1, va1,
                                       out_w, out_b, g2, be2, mu2, va2, ws);
  msg3d_main<<<N_B * NT, 256, 0, stream>>>(x, ws, out);
}